// Round 15
// baseline (112.544 us; speedup 1.0000x reference)
//
#include <hip/hip_runtime.h>
#include <hip/hip_fp16.h>
#include <math.h>

#define KS   15
#define RAD  7
#define L    160
#define VOL  (L*L*L)
#define NB   4
#define WTL  32             // w-cols per k_wh block
#define HTL  80             // output h-rows per k_wh block
#define HALO (HTL + 2*RAD)  // 94
#define LDA  34             // LDS row stride in floats (even, bank-skewed)
#define RPT  5              // h-rows per thread in stage B (16 ty * 5 = 80)
#define DT   40             // k_d d-chunk per thread
#define NBLK (5*10*16)      // k_d grid blocks = 800

typedef float fx2 __attribute__((ext_vector_type(2)));
typedef float fx4 __attribute__((ext_vector_type(4)));

struct Taps {
    float g[KS];   // normalized 1D gaussian (symmetric)
    float h[KS];   // (x^2 - s^2)/s^4 * g (symmetric)
    float m;       // kernel mean (subtracted constant)
    float scale;   // 1 / (N * VOL)
};

// zero-padded fx4 load from a row of length L
__device__ __forceinline__ fx4 ld4z(const float* __restrict__ p, int w) {
    if (w >= 0 && w + 3 < L) return *reinterpret_cast<const fx4*>(p + w);
    fx4 r;
    r.x = (w     >= 0 && w     < L) ? p[w]     : 0.f;
    r.y = (w + 1 >= 0 && w + 1 < L) ? p[w + 1] : 0.f;
    r.z = (w + 2 >= 0 && w + 2 < L) ? p[w + 2] : 0.f;
    r.w = (w + 3 >= 0 && w + 3 < L) ? p[w + 3] : 0.f;
    return r;
}

// ============ Kernel 1: diff + W-conv + H-conv fused (R11 best config) ======
// grid (10 = 5 w-tiles x 2 h-tiles, 160 d, 4 n), block 256. LDS ~31.5 KB.
// Separate sA/sB (measured-best bank behavior), LDA=34 skew.
// XCD swizzle: the 10 blocks of one (d,n) plane-group land on ONE XCD.
// Writes PQ (half2) and R (half), TRANSPOSED [n][h][d][w].
__global__ __launch_bounds__(256) void k_wh(const float* __restrict__ pred,
                                            const float* __restrict__ tgt,
                                            __half2* __restrict__ PQ,
                                            __half* __restrict__ Rb,
                                            Taps tp) {
    __shared__ float   sA[HALO][LDA];
    __shared__ float   sB[HALO][LDA];
    __shared__ __half2 sC[HALO][LDA / 2];

    // ---- bijective XCD-chunked remap (nwg=6400, 8 XCDs, chunk=800) ----
    const int pflat = blockIdx.x + 10 * (blockIdx.y + 160 * blockIdx.z);
    const int wlog  = (pflat & 7) * 800 + (pflat >> 3);
    const int bxs   = wlog % 10;
    const int bys   = (wlog / 10) % 160;
    const int bzs   = wlog / 1600;

    const int tid = threadIdx.x;
    const int wt  = bxs >> 1;                 // 0..4
    const int ht  = bxs & 1;                  // 0..1
    const int wb  = wt * WTL;
    const int h0  = ht * HTL;
    const int d   = bys;
    const int n   = bzs;
    const size_t nbase = (size_t)n * VOL;
    const float* __restrict__ pro = pred + nbase + (size_t)d * L * L;
    const float* __restrict__ tro = tgt  + nbase + (size_t)d * L * L;
    const bool wedge = (wt == 0) || (wt == 4);

    // ---- Stage A: diff + W-conv. 94 rows x 4 groups, 8 outputs/task ----
    for (int task = tid; task < HALO * 4; task += 256) {
        const int r  = task >> 2;             // 0..93
        const int j2 = task & 3;              // 0..3
        const int h  = h0 - RAD + r;
        if (h >= 0 && h < L) {
            const float* pr = pro + h * L;
            const float* tr = tro + h * L;
            const int w0 = wb + 8 * j2 - 8;   // 24-float window base
            float dv[24];
            if (!wedge) {
#pragma unroll
                for (int q = 0; q < 6; ++q) {
                    fx4 pv = *reinterpret_cast<const fx4*>(pr + w0 + 4 * q);
                    fx4 tv = *reinterpret_cast<const fx4*>(tr + w0 + 4 * q);
                    fx4 dd = pv - tv;         // packed f32 sub
                    dv[4*q+0] = dd.x; dv[4*q+1] = dd.y;
                    dv[4*q+2] = dd.z; dv[4*q+3] = dd.w;
                }
            } else {
#pragma unroll
                for (int q = 0; q < 6; ++q) {
                    fx4 pv = ld4z(pr, w0 + 4 * q);
                    fx4 tv = ld4z(tr, w0 + 4 * q);
                    fx4 dd = pv - tv;
                    dv[4*q+0] = dd.x; dv[4*q+1] = dd.y;
                    dv[4*q+2] = dd.z; dv[4*q+3] = dd.w;
                }
            }
            // conv over k-pairs with packed f32 (v_pk_fma_f32)
#pragma unroll
            for (int kp = 0; kp < 8; kp += 2) {
                fx2 mid = {dv[kp + 8], dv[kp + 9]};
                fx2 aa = tp.g[7] * mid;
                fx2 bb = tp.h[7] * mid;
                fx2 cc = mid;
#pragma unroll
                for (int u = 0; u < 7; ++u) {         // symmetric taps
                    fx2 sl = {dv[kp + 1 + u],  dv[kp + 2 + u]};
                    fx2 sr = {dv[kp + 15 - u], dv[kp + 16 - u]};
                    fx2 s  = sl + sr;
                    aa += tp.g[u] * s;
                    bb += tp.h[u] * s;
                    cc += s;
                }
                *reinterpret_cast<fx2*>(&sA[r][8*j2 + kp]) = aa;
                *reinterpret_cast<fx2*>(&sB[r][8*j2 + kp]) = bb;
                sC[r][(8*j2 + kp) >> 1] = __floats2half2_rn(cc.x, cc.y);
            }
        } else {
#pragma unroll
            for (int kp = 0; kp < 8; kp += 2) {
                fx2 z = {0.f, 0.f};
                *reinterpret_cast<fx2*>(&sA[r][8*j2 + kp]) = z;
                *reinterpret_cast<fx2*>(&sB[r][8*j2 + kp]) = z;
                sC[r][(8*j2 + kp) >> 1] = __floats2half2_rn(0.f, 0.f);
            }
        }
    }
    __syncthreads();

    // ---- Stage B: H-conv; thread owns 2 w-cols x RPT h-rows ----
    {
        const int wg = tid & 15;              // 0..15 -> w = wb + 2*wg, +1
        const int ty = tid >> 4;              // 0..15 -> h = h0 + 5*ty .. +4
        fx2 p[RPT], q[RPT], rb[RPT];
#pragma unroll
        for (int k = 0; k < RPT; ++k) { p[k] = 0.f; q[k] = 0.f; rb[k] = 0.f; }
#pragma unroll
        for (int jr = 0; jr < RPT + 2 * RAD; ++jr) {   // 19 rows
            const int srow = RPT * ty + jr;
            fx2 va = *reinterpret_cast<const fx2*>(&sA[srow][2*wg]);
            fx2 vb = *reinterpret_cast<const fx2*>(&sB[srow][2*wg]);
            float2 cf = __half22float2(sC[srow][wg]);
            fx2 vc = {cf.x, cf.y};
#pragma unroll
            for (int k = 0; k < RPT; ++k) {
                const int t = jr - k;
                if (t >= 0 && t < KS) {               // compile-time resolved
                    p[k]  += tp.g[t] * va;
                    q[k]  += tp.h[t] * va + tp.g[t] * vb;
                    rb[k] += vc;
                }
            }
        }
#pragma unroll
        for (int k = 0; k < RPT; ++k) {
            const int h = h0 + RPT * ty + k;
            const size_t o = nbase + ((size_t)h * L + d) * L + wb + 2*wg;
            __half2 pq[2];
            pq[0] = __floats2half2_rn(p[k].x, q[k].x);
            pq[1] = __floats2half2_rn(p[k].y, q[k].y);
            *reinterpret_cast<int2*>(&PQ[o]) = *reinterpret_cast<int2*>(pq);
            __half2 rr = __floats2half2_rn(rb[k].x, rb[k].y);
            *reinterpret_cast<__half2*>(&Rb[o]) = rr;
        }
    }
}

// ============ Kernel 2: D-conv streaming + |.| + block reduce ================
// grid (5,10,16) = 800 blocks. XCD swizzle: the 4 d-chunks of one (bx,by,n)
// group (which share +-7 halo planes) land on one XCD. Cache-fed, ~roofline.
__global__ __launch_bounds__(512) void k_d(const __half2* __restrict__ PQ,
                                           const __half* __restrict__ R,
                                           float* __restrict__ partial,
                                           Taps tp) {
    // bijective remap: nwg=800, chunk=100; logical order has dc fastest.
    const int pflat = blockIdx.x + 5 * (blockIdx.y + 10 * blockIdx.z);
    const int wlog  = (pflat & 7) * 100 + (pflat >> 3);
    const int dc    = wlog & 3;
    const int rest  = wlog >> 2;
    const int bx    = rest % 5;
    const int by    = (rest / 5) % 10;
    const int n     = rest / 50;

    const int tx = threadIdx.x;          // 0..31 (w)
    const int ty = threadIdx.y;          // 0..15 (h)
    const int w  = bx * 32 + tx;
    const int h  = by * 16 + ty;
    const int d0 = dc * DT;

    const size_t base = (size_t)n * VOL + ((size_t)h * L) * L + w;
    const __half2* PQp = PQ + base;
    const __half*  Rp  = R  + base;

    float rp[KS], rq[KS], rc[KS];
    float box = 0.f;

#pragma unroll
    for (int i = 0; i < KS - 1; ++i) {
        int s = d0 - RAD + i;
        bool ok = (s >= 0);
        int off = s * L;
        float2 pq = make_float2(0.f, 0.f);
        float vc = 0.f;
        if (ok) {
            pq = __half22float2(PQp[off]);
            vc = __half2float(Rp[off]);
        }
        rp[i] = pq.x; rq[i] = pq.y; rc[i] = vc;
        box += vc;
    }

    float acc = 0.f;
#pragma unroll
    for (int k = 0; k < DT; ++k) {
        int s = d0 + RAD + k;
        bool ok = (s < L);
        int off = s * L;
        float2 pq = make_float2(0.f, 0.f);
        float vc = 0.f;
        if (ok) {
            pq = __half22float2(PQp[off]);
            vc = __half2float(Rp[off]);
        }
        const int ri = (KS - 1 + k) % KS;
        rp[ri] = pq.x; rq[ri] = pq.y; rc[ri] = vc;
        box += vc;

        float f = 0.f;
#pragma unroll
        for (int t = 0; t < KS; ++t) {
            const int ii = (k + t) % KS;
            f += tp.h[t] * rp[ii] + tp.g[t] * rq[ii];
        }
        f -= tp.m * box;
        acc += fabsf(f);

        box -= rc[k % KS];
    }
    acc *= tp.scale;

#pragma unroll
    for (int off = 32; off > 0; off >>= 1) acc += __shfl_down(acc, off);

    __shared__ float wsum[8];
    const int tid  = ty * 32 + tx;
    const int lane = tid & 63;
    const int wid  = tid >> 6;
    if (lane == 0) wsum[wid] = acc;
    __syncthreads();
    if (wid == 0) {
        float v = (lane < 8) ? wsum[lane] : 0.f;
#pragma unroll
        for (int off = 4; off > 0; off >>= 1) v += __shfl_down(v, off);
        if (lane == 0) {
            partial[wlog] = v;   // wlog is a bijection of flat id -> unique slot
        }
    }
}

// ============ Final: sum 800 partials, single block, plain store ============
__global__ __launch_bounds__(1024) void k_reduce(const float* __restrict__ partial,
                                                 float* __restrict__ out) {
    float v = 0.f;
    for (int i = threadIdx.x; i < NBLK; i += 1024) v += partial[i];
#pragma unroll
    for (int off = 32; off > 0; off >>= 1) v += __shfl_down(v, off);

    __shared__ float wsum[16];
    const int lane = threadIdx.x & 63;
    const int wid  = threadIdx.x >> 6;
    if (lane == 0) wsum[wid] = v;
    __syncthreads();
    if (wid == 0) {
        float s = (lane < 16) ? wsum[lane] : 0.f;
#pragma unroll
        for (int off = 8; off > 0; off >>= 1) s += __shfl_down(s, off);
        if (lane == 0) out[0] = s;
    }
}

extern "C" void kernel_launch(void* const* d_in, const int* in_sizes, int n_in,
                              void* d_out, int out_size, void* d_ws, size_t ws_size,
                              hipStream_t stream) {
    const float* pred = (const float*)d_in[0];
    const float* tgt  = (const float*)d_in[1];
    float* out = (float*)d_out;

    Taps tp;
    const double sigma = 1.5;
    double g1[KS], S = 0.0;
    for (int i = 0; i < KS; ++i) {
        double x = (double)(i - RAD);
        g1[i] = exp(-x * x / (2.0 * sigma * sigma));
        S += g1[i];
    }
    double sumH = 0.0;
    for (int i = 0; i < KS; ++i) {
        double x = (double)(i - RAD);
        double G = g1[i] / S;
        double H = (x * x - sigma * sigma) / (sigma * sigma * sigma * sigma) * G;
        tp.g[i] = (float)G;
        tp.h[i] = (float)H;
        sumH += H;
    }
    tp.m     = (float)(3.0 * sumH / (double)(KS * KS * KS));
    tp.scale = 1.0f / ((float)NB * (float)VOL);

    // ws layout (bytes): PQ half2 [NB*VOL*4] | R half [NB*VOL*2] | partial f32
    char* wsb = (char*)d_ws;
    __half2* PQ      = (__half2*)wsb;
    __half*  Rb      = (__half*)(wsb + (size_t)NB * VOL * 4);
    float*   partial = (float*)(wsb + (size_t)NB * VOL * 6);

    k_wh<<<dim3(10, L, NB), dim3(256), 0, stream>>>(pred, tgt, PQ, Rb, tp);
    k_d<<<dim3(5, 10, NB * 4), dim3(32, 16), 0, stream>>>(PQ, Rb, partial, tp);
    k_reduce<<<1, 1024, 0, stream>>>(partial, out);
}

// Round 16
// 104.880 us; speedup vs baseline: 1.0731x; 1.0731x over previous
//
#include <hip/hip_runtime.h>
#include <hip/hip_fp16.h>
#include <math.h>

#define KS   15
#define RAD  7
#define L    160
#define VOL  (L*L*L)
#define NB   4
#define WTL  32             // w-cols per k_wh block
#define HTL  80             // output h-rows per k_wh block
#define HALO (HTL + 2*RAD)  // 94
#define LDA  34             // LDS row stride in floats (even, bank-skewed)
#define RPT  5              // h-rows per thread in stage B (16 ty * 5 = 80)
#define DT   40             // k_d d-chunk per thread
#define NBLK (5*10*16)      // k_d grid blocks = 800

typedef float fx2 __attribute__((ext_vector_type(2)));
typedef float fx4 __attribute__((ext_vector_type(4)));

struct Taps {
    float g[KS];   // normalized 1D gaussian (symmetric)
    float h[KS];   // (x^2 - s^2)/s^4 * g (symmetric)
    float m;       // kernel mean (subtracted constant)
    float scale;   // 1 / (N * VOL)
};

// zero-padded fx4 load from a row of length L
__device__ __forceinline__ fx4 ld4z(const float* __restrict__ p, int w) {
    if (w >= 0 && w + 3 < L) return *reinterpret_cast<const fx4*>(p + w);
    fx4 r;
    r.x = (w     >= 0 && w     < L) ? p[w]     : 0.f;
    r.y = (w + 1 >= 0 && w + 1 < L) ? p[w + 1] : 0.f;
    r.z = (w + 2 >= 0 && w + 2 < L) ? p[w + 2] : 0.f;
    r.w = (w + 3 >= 0 && w + 3 < L) ? p[w + 3] : 0.f;
    return r;
}

// ============ Kernel 1: diff + W-conv + H-conv fused ========================
// grid (10 = 5 w-tiles x 2 h-tiles, 160 d, 4 n), block 256. LDS ~31.5 KB.
// Stage B: rows in registers + SYMMETRIC tap folding (40 pk-ops/output vs 60)
// + incremental box-sum. Same LDS read count; -33% stage-B math.
// XCD swizzle: the 10 blocks of one (d,n) plane-group land on ONE XCD.
// Writes PQ (half2) and R (half), TRANSPOSED [n][h][d][w].
__global__ __launch_bounds__(256) void k_wh(const float* __restrict__ pred,
                                            const float* __restrict__ tgt,
                                            __half2* __restrict__ PQ,
                                            __half* __restrict__ Rb,
                                            Taps tp) {
    __shared__ float   sA[HALO][LDA];
    __shared__ float   sB[HALO][LDA];
    __shared__ __half2 sC[HALO][LDA / 2];

    // ---- bijective XCD-chunked remap (nwg=6400, 8 XCDs, chunk=800) ----
    const int pflat = blockIdx.x + 10 * (blockIdx.y + 160 * blockIdx.z);
    const int wlog  = (pflat & 7) * 800 + (pflat >> 3);
    const int bxs   = wlog % 10;
    const int bys   = (wlog / 10) % 160;
    const int bzs   = wlog / 1600;

    const int tid = threadIdx.x;
    const int wt  = bxs >> 1;                 // 0..4
    const int ht  = bxs & 1;                  // 0..1
    const int wb  = wt * WTL;
    const int h0  = ht * HTL;
    const int d   = bys;
    const int n   = bzs;
    const size_t nbase = (size_t)n * VOL;
    const float* __restrict__ pro = pred + nbase + (size_t)d * L * L;
    const float* __restrict__ tro = tgt  + nbase + (size_t)d * L * L;
    const bool wedge = (wt == 0) || (wt == 4);

    // ---- Stage A: diff + W-conv. 94 rows x 4 groups, 8 outputs/task ----
    for (int task = tid; task < HALO * 4; task += 256) {
        const int r  = task >> 2;             // 0..93
        const int j2 = task & 3;              // 0..3
        const int h  = h0 - RAD + r;
        if (h >= 0 && h < L) {
            const float* pr = pro + h * L;
            const float* tr = tro + h * L;
            const int w0 = wb + 8 * j2 - 8;   // 24-float window base
            float dv[24];
            if (!wedge) {
#pragma unroll
                for (int q = 0; q < 6; ++q) {
                    fx4 pv = *reinterpret_cast<const fx4*>(pr + w0 + 4 * q);
                    fx4 tv = *reinterpret_cast<const fx4*>(tr + w0 + 4 * q);
                    fx4 dd = pv - tv;         // packed f32 sub
                    dv[4*q+0] = dd.x; dv[4*q+1] = dd.y;
                    dv[4*q+2] = dd.z; dv[4*q+3] = dd.w;
                }
            } else {
#pragma unroll
                for (int q = 0; q < 6; ++q) {
                    fx4 pv = ld4z(pr, w0 + 4 * q);
                    fx4 tv = ld4z(tr, w0 + 4 * q);
                    fx4 dd = pv - tv;
                    dv[4*q+0] = dd.x; dv[4*q+1] = dd.y;
                    dv[4*q+2] = dd.z; dv[4*q+3] = dd.w;
                }
            }
            // conv over k-pairs with packed f32 (v_pk_fma_f32)
#pragma unroll
            for (int kp = 0; kp < 8; kp += 2) {
                fx2 mid = {dv[kp + 8], dv[kp + 9]};
                fx2 aa = tp.g[7] * mid;
                fx2 bb = tp.h[7] * mid;
                fx2 cc = mid;
#pragma unroll
                for (int u = 0; u < 7; ++u) {         // symmetric taps
                    fx2 sl = {dv[kp + 1 + u],  dv[kp + 2 + u]};
                    fx2 sr = {dv[kp + 15 - u], dv[kp + 16 - u]};
                    fx2 s  = sl + sr;
                    aa += tp.g[u] * s;
                    bb += tp.h[u] * s;
                    cc += s;
                }
                *reinterpret_cast<fx2*>(&sA[r][8*j2 + kp]) = aa;
                *reinterpret_cast<fx2*>(&sB[r][8*j2 + kp]) = bb;
                sC[r][(8*j2 + kp) >> 1] = __floats2half2_rn(cc.x, cc.y);
            }
        } else {
#pragma unroll
            for (int kp = 0; kp < 8; kp += 2) {
                fx2 z = {0.f, 0.f};
                *reinterpret_cast<fx2*>(&sA[r][8*j2 + kp]) = z;
                *reinterpret_cast<fx2*>(&sB[r][8*j2 + kp]) = z;
                sC[r][(8*j2 + kp) >> 1] = __floats2half2_rn(0.f, 0.f);
            }
        }
    }
    __syncthreads();

    // ---- Stage B: H-conv; rows in regs, symmetric fold, incremental box ----
    {
        const int wg = tid & 15;              // 0..15 -> w = wb + 2*wg, +1
        const int ty = tid >> 4;              // 0..15 -> h = h0 + 5*ty .. +4
        const int br = RPT * ty;              // first LDS row

        fx2 va[19], vb[19];
        fx2 vcl[4], vch[4];                   // C rows 0..3 and 15..18
        fx2 box = {0.f, 0.f};
#pragma unroll
        for (int jr = 0; jr < RPT + 2 * RAD; ++jr) {   // 19 rows, same reads
            const int srow = br + jr;
            va[jr] = *reinterpret_cast<const fx2*>(&sA[srow][2*wg]);
            vb[jr] = *reinterpret_cast<const fx2*>(&sB[srow][2*wg]);
            float2 cf = __half22float2(sC[srow][wg]);
            fx2 vc = {cf.x, cf.y};
            if (jr < KS) box += vc;           // compile-time predicates
            if (jr < 4)  vcl[jr] = vc;
            if (jr >= KS) vch[jr - KS] = vc;
        }

#pragma unroll
        for (int k = 0; k < RPT; ++k) {
            fx2 p = tp.g[7] * va[k + 7];
            fx2 q = tp.h[7] * va[k + 7] + tp.g[7] * vb[k + 7];
#pragma unroll
            for (int u = 0; u < 7; ++u) {     // symmetric taps (g,h both)
                fx2 sa = va[k + u] + va[k + 14 - u];
                fx2 sb = vb[k + u] + vb[k + 14 - u];
                p += tp.g[u] * sa;
                q += tp.h[u] * sa + tp.g[u] * sb;
            }
            const int h = h0 + br + k;
            const size_t o = nbase + ((size_t)h * L + d) * L + wb + 2 * wg;
            __half2 pq[2];
            pq[0] = __floats2half2_rn(p.x, q.x);
            pq[1] = __floats2half2_rn(p.y, q.y);
            *reinterpret_cast<int2*>(&PQ[o]) = *reinterpret_cast<int2*>(pq);
            __half2 rr = __floats2half2_rn(box.x, box.y);
            *reinterpret_cast<__half2*>(&Rb[o]) = rr;
            if (k < RPT - 1) box += vch[k] - vcl[k];   // incremental box
        }
    }
}

// ============ Kernel 2: D-conv streaming + |.| + block reduce ================
// grid (5,10,16) = 800 blocks. XCD swizzle: the 4 d-chunks of one (bx,by,n)
// group (which share +-7 halo planes) land on one XCD. Cache-fed, ~roofline.
__global__ __launch_bounds__(512) void k_d(const __half2* __restrict__ PQ,
                                           const __half* __restrict__ R,
                                           float* __restrict__ partial,
                                           Taps tp) {
    // bijective remap: nwg=800, chunk=100; logical order has dc fastest.
    const int pflat = blockIdx.x + 5 * (blockIdx.y + 10 * blockIdx.z);
    const int wlog  = (pflat & 7) * 100 + (pflat >> 3);
    const int dc    = wlog & 3;
    const int rest  = wlog >> 2;
    const int bx    = rest % 5;
    const int by    = (rest / 5) % 10;
    const int n     = rest / 50;

    const int tx = threadIdx.x;          // 0..31 (w)
    const int ty = threadIdx.y;          // 0..15 (h)
    const int w  = bx * 32 + tx;
    const int h  = by * 16 + ty;
    const int d0 = dc * DT;

    const size_t base = (size_t)n * VOL + ((size_t)h * L) * L + w;
    const __half2* PQp = PQ + base;
    const __half*  Rp  = R  + base;

    float rp[KS], rq[KS], rc[KS];
    float box = 0.f;

#pragma unroll
    for (int i = 0; i < KS - 1; ++i) {
        int s = d0 - RAD + i;
        bool ok = (s >= 0);
        int off = s * L;
        float2 pq = make_float2(0.f, 0.f);
        float vc = 0.f;
        if (ok) {
            pq = __half22float2(PQp[off]);
            vc = __half2float(Rp[off]);
        }
        rp[i] = pq.x; rq[i] = pq.y; rc[i] = vc;
        box += vc;
    }

    float acc = 0.f;
#pragma unroll
    for (int k = 0; k < DT; ++k) {
        int s = d0 + RAD + k;
        bool ok = (s < L);
        int off = s * L;
        float2 pq = make_float2(0.f, 0.f);
        float vc = 0.f;
        if (ok) {
            pq = __half22float2(PQp[off]);
            vc = __half2float(Rp[off]);
        }
        const int ri = (KS - 1 + k) % KS;
        rp[ri] = pq.x; rq[ri] = pq.y; rc[ri] = vc;
        box += vc;

        float f = 0.f;
#pragma unroll
        for (int t = 0; t < KS; ++t) {
            const int ii = (k + t) % KS;
            f += tp.h[t] * rp[ii] + tp.g[t] * rq[ii];
        }
        f -= tp.m * box;
        acc += fabsf(f);

        box -= rc[k % KS];
    }
    acc *= tp.scale;

#pragma unroll
    for (int off = 32; off > 0; off >>= 1) acc += __shfl_down(acc, off);

    __shared__ float wsum[8];
    const int tid  = ty * 32 + tx;
    const int lane = tid & 63;
    const int wid  = tid >> 6;
    if (lane == 0) wsum[wid] = acc;
    __syncthreads();
    if (wid == 0) {
        float v = (lane < 8) ? wsum[lane] : 0.f;
#pragma unroll
        for (int off = 4; off > 0; off >>= 1) v += __shfl_down(v, off);
        if (lane == 0) {
            partial[wlog] = v;   // wlog is a bijection of flat id -> unique slot
        }
    }
}

// ============ Final: sum 800 partials, single block, plain store ============
__global__ __launch_bounds__(1024) void k_reduce(const float* __restrict__ partial,
                                                 float* __restrict__ out) {
    float v = 0.f;
    for (int i = threadIdx.x; i < NBLK; i += 1024) v += partial[i];
#pragma unroll
    for (int off = 32; off > 0; off >>= 1) v += __shfl_down(v, off);

    __shared__ float wsum[16];
    const int lane = threadIdx.x & 63;
    const int wid  = threadIdx.x >> 6;
    if (lane == 0) wsum[wid] = v;
    __syncthreads();
    if (wid == 0) {
        float s = (lane < 16) ? wsum[lane] : 0.f;
#pragma unroll
        for (int off = 8; off > 0; off >>= 1) s += __shfl_down(s, off);
        if (lane == 0) out[0] = s;
    }
}

extern "C" void kernel_launch(void* const* d_in, const int* in_sizes, int n_in,
                              void* d_out, int out_size, void* d_ws, size_t ws_size,
                              hipStream_t stream) {
    const float* pred = (const float*)d_in[0];
    const float* tgt  = (const float*)d_in[1];
    float* out = (float*)d_out;

    Taps tp;
    const double sigma = 1.5;
    double g1[KS], S = 0.0;
    for (int i = 0; i < KS; ++i) {
        double x = (double)(i - RAD);
        g1[i] = exp(-x * x / (2.0 * sigma * sigma));
        S += g1[i];
    }
    double sumH = 0.0;
    for (int i = 0; i < KS; ++i) {
        double x = (double)(i - RAD);
        double G = g1[i] / S;
        double H = (x * x - sigma * sigma) / (sigma * sigma * sigma * sigma) * G;
        tp.g[i] = (float)G;
        tp.h[i] = (float)H;
        sumH += H;
    }
    tp.m     = (float)(3.0 * sumH / (double)(KS * KS * KS));
    tp.scale = 1.0f / ((float)NB * (float)VOL);

    // ws layout (bytes): PQ half2 [NB*VOL*4] | R half [NB*VOL*2] | partial f32
    char* wsb = (char*)d_ws;
    __half2* PQ      = (__half2*)wsb;
    __half*  Rb      = (__half*)(wsb + (size_t)NB * VOL * 4);
    float*   partial = (float*)(wsb + (size_t)NB * VOL * 6);

    k_wh<<<dim3(10, L, NB), dim3(256), 0, stream>>>(pred, tgt, PQ, Rb, tp);
    k_d<<<dim3(5, 10, NB * 4), dim3(32, 16), 0, stream>>>(PQ, Rb, partial, tp);
    k_reduce<<<1, 1024, 0, stream>>>(partial, out);
}